// Round 5
// baseline (61.881 us; speedup 1.0000x reference)
//
#include <hip/hip_runtime.h>

typedef __bf16 bf16x8 __attribute__((ext_vector_type(8)));
typedef float f32x4 __attribute__((ext_vector_type(4)));
typedef unsigned int uint;

#define XA_STR 152   // shorts; 304B rows, 16B-aligned

union Frag { __bf16 b[8]; bf16x8 v; unsigned short u[8]; };

__device__ __forceinline__ unsigned short bfbits(float f) {
  union { __bf16 h; unsigned short s; } c; c.h = (__bf16)f; return c.s;
}
__device__ __forceinline__ float bf2f(unsigned short h) {
  return __uint_as_float(((uint)h) << 16);
}

// counted wait + barrier: keeps later stages' global_load_lds in flight
#define WAIT_BAR(N) asm volatile("s_waitcnt vmcnt(" #N ") lgkmcnt(0)\n\ts_barrier" ::: "memory")
#define LGKM_BAR()  asm volatile("s_waitcnt lgkmcnt(0)\n\ts_barrier" ::: "memory")

// dst[s][b][f] (bf16) = src[b][f][s]   (B=64, F=128, S=128)
// (for layer 2 this implements the required axis swap: xt2[d1][b][s1] = x1[b,s1,d1])
template <typename T>
__global__ __launch_bounds__(256) void transpose_in(const T* __restrict__ src,
                                                    unsigned short* __restrict__ dst) {
  __shared__ unsigned short tile[64][68];
  const int b  = blockIdx.x >> 2;
  const int f0 = ((blockIdx.x >> 1) & 1) * 64;
  const int s0 = (blockIdx.x & 1) * 64;
  const int j = threadIdx.x & 63, i0 = threadIdx.x >> 6;
  const T* sp = src + b * 16384 + f0 * 128 + s0 + j;
#pragma unroll
  for (int p = 0; p < 16; ++p) {
    const int i = i0 + p * 4;
    if constexpr (sizeof(T) == 4) tile[i][j] = bfbits((float)sp[i * 128]);
    else                          tile[i][j] = (unsigned short)sp[i * 128];
  }
  __syncthreads();
  unsigned short* dp = dst + s0 * 8192 + b * 128 + f0 + j;
#pragma unroll
  for (int p = 0; p < 16; ++p) {
    const int i = i0 + p * 4;
    dp[(size_t)i * 8192] = tile[j][i];
  }
}

// Block = (slot s, E-quarter q): 512 threads = 8 waves; wave owns 16 weight
// cols. Weights stream HBM -> LDS via global_load_lds, 3-buffer ring,
// depth-2 counted-vmcnt pipeline (never drained to 0 mid-loop).
__global__ __launch_bounds__(512, 4) void mlp_main(
    const unsigned short* __restrict__ Xt,   // [128][64][128] bf16
    const float* __restrict__ Wu, const float* __restrict__ bu,
    const float* __restrict__ Wg, const float* __restrict__ bg,
    const float* __restrict__ Wd,
    unsigned short* __restrict__ partial)    // [512][64][128] bf16
{
  const int bid = blockIdx.x;
  const int s = bid >> 2, q = bid & 3;
  const int tid = threadIdx.x;
  const int wv = tid >> 6, lane = tid & 63;
  const int l16 = lane & 15, lg = lane >> 4;
  const int col = wv * 16 + l16;

  __shared__ __align__(16) float wb[3][4096];              // 3 x 16KB ring
  __shared__ __align__(16) unsigned short xa[64 * XA_STR]; // X then A2

  const float* WuS = Wu + (size_t)s * 65536 + q * 128;   // rows k, stride 512
  const float* WgS = Wg + (size_t)s * 65536 + q * 128;
  const float* WdS = Wd + (size_t)s * 65536 + (size_t)q * 16384;  // stride 128

  // stage one 32x128 fp32 slice into ring buffer bb (pre-swizzled source:
  // LDS[k][cd] = global[k][cd ^ 16*((k>>3)&1)], 16B-chunk granularity)
  auto ISSUE = [&](const float* base, int rs, float* bb) {
#pragma unroll
    for (int r = 0; r < 2; ++r) {
      const int p = (r << 9) + tid;          // 16B chunk index 0..1023
      const int k = p >> 5, ch = p & 31;
      const int chs = ch ^ (((k >> 3) & 1) << 2);
      __builtin_amdgcn_global_load_lds(
          (const __attribute__((address_space(1))) void*)(base + (size_t)k * rs + (chs << 2)),
          (__attribute__((address_space(3))) void*)(bb + (p << 2)), 16, 0, 0);
    }
  };

  Frag a[4];
  auto LOADA = [&](int kk) {
#pragma unroll
    for (int mt = 0; mt < 4; ++mt)
      a[mt].v = *(const bf16x8*)&xa[(mt * 16 + l16) * XA_STR + ((kk * 4 + lg) << 3)];
  };

  const int cswz = col ^ ((lg & 1) << 4);    // read-side inverse swizzle
  auto BFRAG = [&](const float* bb) {
    Frag f;
    const float* bp = bb + (lg << 3) * 128 + cswz;
#pragma unroll
    for (int j = 0; j < 8; ++j) f.b[j] = (__bf16)bp[j * 128];
    return f;
  };

  f32x4 au[4] = {}, ag[4] = {}, ad[4] = {};
  auto MFMA4 = [&](const Frag& f, f32x4* acc) {
#pragma unroll
    for (int mt = 0; mt < 4; ++mt)
      acc[mt] = __builtin_amdgcn_mfma_f32_16x16x32_bf16(a[mt].v, f.v, acc[mt], 0, 0, 0);
  };

  // ---- prologue ----
  uint4 xv[2];
#pragma unroll
  for (int cc = 0; cc < 2; ++cc) {
    const int p = (cc << 9) + tid;
    const int m = p >> 4, ch = p & 15;
    xv[cc] = *(const uint4*)(Xt + (size_t)s * 8192 + m * 128 + (ch << 3));
  }
  const float buv = bu[s * 512 + q * 128 + col];
  const float bgv = bg[s * 512 + q * 128 + col];
  __builtin_amdgcn_sched_barrier(0);
  ISSUE(WuS, 512, wb[0]);                    // S0
  ISSUE(WgS, 512, wb[1]);                    // S1
  __builtin_amdgcn_sched_barrier(0);
#pragma unroll
  for (int cc = 0; cc < 2; ++cc) {
    const int p = (cc << 9) + tid;
    const int m = p >> 4, ch = p & 15;
    *(uint4*)&xa[m * XA_STR + (ch << 3)] = xv[cc];
  }

  // ---- 12-stage pipeline ----
  WAIT_BAR(2);                               // S0 resident
  LOADA(0); { Frag f = BFRAG(wb[0]); MFMA4(f, au); }
  ISSUE(WuS + 32 * 512, 512, wb[2]);         // S2
  WAIT_BAR(2);                               // S1
  { Frag f = BFRAG(wb[1]); MFMA4(f, ag); }
  ISSUE(WgS + 32 * 512, 512, wb[0]);         // S3
  WAIT_BAR(2);                               // S2
  LOADA(1); { Frag f = BFRAG(wb[2]); MFMA4(f, au); }
  ISSUE(WuS + 64 * 512, 512, wb[1]);         // S4
  WAIT_BAR(2);                               // S3
  { Frag f = BFRAG(wb[0]); MFMA4(f, ag); }
  ISSUE(WgS + 64 * 512, 512, wb[2]);         // S5
  WAIT_BAR(2);                               // S4
  LOADA(2); { Frag f = BFRAG(wb[1]); MFMA4(f, au); }
  ISSUE(WuS + 96 * 512, 512, wb[0]);         // S6
  WAIT_BAR(2);                               // S5
  { Frag f = BFRAG(wb[2]); MFMA4(f, ag); }
  ISSUE(WgS + 96 * 512, 512, wb[1]);         // S7
  WAIT_BAR(2);                               // S6
  LOADA(3); { Frag f = BFRAG(wb[0]); MFMA4(f, au); }
  ISSUE(WdS, 128, wb[2]);                    // S8
  WAIT_BAR(2);                               // S7
  { Frag f = BFRAG(wb[1]); MFMA4(f, ag); }
  ISSUE(WdS + 32 * 128, 128, wb[0]);         // S9

  // silu epilogue -> A2 into xa (X region dead after S7's reads)
  float a2v[4][4];
#pragma unroll
  for (int mt = 0; mt < 4; ++mt)
#pragma unroll
    for (int r = 0; r < 4; ++r) {
      const float uv = au[mt][r] + buv;
      const float gv = ag[mt][r] + bgv;
      a2v[mt][r] = uv * (gv / (1.f + __expf(-gv)));
    }
  LGKM_BAR();                                // all waves done reading X
#pragma unroll
  for (int mt = 0; mt < 4; ++mt)
#pragma unroll
    for (int r = 0; r < 4; ++r)
      xa[(mt * 16 + lg * 4 + r) * XA_STR + col] = bfbits(a2v[mt][r]);

  WAIT_BAR(2);                               // S8 resident; A2 published
  LOADA(0); { Frag f = BFRAG(wb[2]); MFMA4(f, ad); }
  ISSUE(WdS + 64 * 128, 128, wb[1]);         // S10
  WAIT_BAR(2);                               // S9
  LOADA(1); { Frag f = BFRAG(wb[0]); MFMA4(f, ad); }
  ISSUE(WdS + 96 * 128, 128, wb[2]);         // S11
  WAIT_BAR(2);                               // S10
  LOADA(2); { Frag f = BFRAG(wb[1]); MFMA4(f, ad); }
  WAIT_BAR(0);                               // S11 (last: full drain ok)
  LOADA(3); { Frag f = BFRAG(wb[2]); MFMA4(f, ad); }

  unsigned short* po = partial + (size_t)bid * 8192;
#pragma unroll
  for (int mt = 0; mt < 4; ++mt)
#pragma unroll
    for (int r = 0; r < 4; ++r)
      po[(mt * 16 + lg * 4 + r) * 128 + col] = bfbits(ad[mt][r]);
}

// sum 4 bf16 partials + bias + residual(xt [s][b][f]), RMSNorm, write [b][s][f]
// (bf16 for layer-1 intermediate, fp32 for final output).
template <typename TO>
__global__ __launch_bounds__(256) void finish(
    const unsigned short* __restrict__ part, const unsigned short* __restrict__ xt,
    const float* __restrict__ bd, const float* __restrict__ scale,
    TO* __restrict__ y)
{
  const int s = blockIdx.x >> 1, half = blockIdx.x & 1;
  const int wvt = threadIdx.x >> 6, lane = threadIdx.x & 63;
  const int d0 = lane * 2;
  const float sc0 = scale[d0], sc1 = scale[d0 + 1];
  const float b0 = bd[s * 128 + d0], b1 = bd[s * 128 + d0 + 1];
  const unsigned short* pb = part + (size_t)s * 4 * 8192;
  const unsigned short* xb = xt + (size_t)s * 8192;
  for (int i = 0; i < 8; ++i) {
    const int b = half * 32 + i * 4 + wvt;
    const uint rx = *(const uint*)(xb + b * 128 + d0);
    float z0 = b0 + bf2f((unsigned short)rx);
    float z1 = b1 + bf2f((unsigned short)(rx >> 16));
#pragma unroll
    for (int p = 0; p < 4; ++p) {
      const uint rp = *(const uint*)(pb + p * 8192 + b * 128 + d0);
      z0 += bf2f((unsigned short)rp);
      z1 += bf2f((unsigned short)(rp >> 16));
    }
    float ss = z0 * z0 + z1 * z1;
#pragma unroll
    for (int off = 32; off; off >>= 1) ss += __shfl_xor(ss, off);
    const float inv = rsqrtf(ss * (1.f / 128.f) + 1e-5f);
    if constexpr (sizeof(TO) == 4) {
      float2 o = make_float2(z0 * inv * sc0, z1 * inv * sc1);
      *(float2*)((float*)y + (size_t)b * 16384 + s * 128 + d0) = o;
    } else {
      const uint o = (uint)bfbits(z0 * inv * sc0) | ((uint)bfbits(z1 * inv * sc1) << 16);
      *(uint*)((unsigned short*)y + (size_t)b * 16384 + s * 128 + d0) = o;
    }
  }
}

extern "C" void kernel_launch(void* const* d_in, const int* in_sizes, int n_in,
                              void* d_out, int out_size, void* d_ws, size_t ws_size,
                              hipStream_t stream) {
  (void)in_sizes; (void)n_in; (void)out_size; (void)ws_size;
  const float* x   = (const float*)d_in[0];
  const float* W1u = (const float*)d_in[1];
  const float* b1u = (const float*)d_in[2];
  const float* W1g = (const float*)d_in[3];
  const float* b1g = (const float*)d_in[4];
  const float* W1d = (const float*)d_in[5];
  const float* b1d = (const float*)d_in[6];
  const float* sc1 = (const float*)d_in[7];
  const float* W2u = (const float*)d_in[8];
  const float* b2u = (const float*)d_in[9];
  const float* W2g = (const float*)d_in[10];
  const float* b2g = (const float*)d_in[11];
  const float* W2d = (const float*)d_in[12];
  const float* b2d = (const float*)d_in[13];
  const float* sc2 = (const float*)d_in[14];
  float* out = (float*)d_out;

  unsigned short* xt   = (unsigned short*)d_ws;          // 2 MB [s][b][f] bf16
  unsigned short* y1   = xt + (size_t)1048576;           // 2 MB [b][s][f] bf16
  unsigned short* part = y1 + (size_t)1048576;           // 8 MB [512][64][128] bf16

  transpose_in<float><<<256, 256, 0, stream>>>(x, xt);
  mlp_main<<<512, 512, 0, stream>>>(xt, W1u, b1u, W1g, b1g, W1d, part);
  finish<unsigned short><<<256, 256, 0, stream>>>(part, xt, b1d, sc1, y1);
  transpose_in<unsigned short><<<256, 256, 0, stream>>>(y1, xt);
  mlp_main<<<512, 512, 0, stream>>>(xt, W2u, b2u, W2g, b2g, W2d, part);
  finish<float><<<256, 256, 0, stream>>>(part, xt, b2d, sc2, out);
}